// Round 1
// baseline (175.777 us; speedup 1.0000x reference)
//
#include <hip/hip_runtime.h>
#include <hip/hip_bf16.h>

typedef __attribute__((ext_vector_type(4))) float f32x4;
typedef __attribute__((ext_vector_type(8))) short bf16x8;

#define T_LEN 2048
#define SPAD 72  // 64 + 8 pad: row stride 144B -> 16B aligned, 2-way bank alias (free)

__device__ inline short f2bf(float f) {
  // round-to-nearest-even f32 -> bf16 (inputs are finite; no NaN handling needed)
  unsigned u = __builtin_bit_cast(unsigned, f);
  return (short)((u + 0x7fffu + ((u >> 16) & 1u)) >> 16);
}

__global__ __launch_bounds__(256) void attn_fwd(const float* __restrict__ qkv,
                                                float* __restrict__ out) {
  __shared__ short Kt[64][SPAD];     // transposed K tile: [s_local][c]
  __shared__ short Vt[64][SPAD];     // natural V tile:    [c][s_local]
  __shared__ short Pb[4][16][SPAD];  // per-wave P tile:   [t_local][s_local]

  const int bid = blockIdx.x;
  const int qt = bid & 31;      // q-tile within head
  const int head = bid >> 5;    // 0..31
  const int b = head >> 3, h = head & 7;

  const size_t base = ((size_t)b * 1536 + h * 64) * T_LEN;
  const float* Q = qkv + base;
  const float* K = qkv + base + (size_t)512 * T_LEN;
  const float* V = qkv + base + (size_t)1024 * T_LEN;
  float* O = out + ((size_t)b * 512 + h * 64) * T_LEN;

  const int tid = threadIdx.x;
  const int wave = tid >> 6;
  const int lane = tid & 63;
  const int l15 = lane & 15;
  const int l4 = lane >> 4;

  const int t0 = qt * 64 + wave * 16;  // this wave's 16 query rows

  // ---- Q fragments (A operand), held in registers for the whole kernel ----
  // A layout: lane provides A[row = lane&15][k = (lane>>4)*8 + j], row = t, k = c
  bf16x8 aq[2];
#pragma unroll
  for (int kk = 0; kk < 2; ++kk)
#pragma unroll
    for (int j = 0; j < 8; ++j) {
      int c = kk * 32 + l4 * 8 + j;
      aq[kk][j] = f2bf(Q[(size_t)c * T_LEN + t0 + l15]);
    }

  // online-softmax state: rows t = t0 + l4*4 + r  (D-layout rows)
  float m_run[4], l_run[4];
  f32x4 o_acc[4];  // [n] = c-subtile (c = 16n + l15), element r = row
#pragma unroll
  for (int r = 0; r < 4; ++r) { m_run[r] = -1e30f; l_run[r] = 0.f; }
#pragma unroll
  for (int n = 0; n < 4; ++n) o_acc[n] = (f32x4){0.f, 0.f, 0.f, 0.f};

  const float inv64 = 0.015625f;  // scale^2 = 1/64 folded into scores

  for (int s0 = 0; s0 < T_LEN; s0 += 64) {
    __syncthreads();  // previous iteration's LDS reads done
    // ---- stage K (transposed) and V (natural) tiles, fp32 -> bf16 ----
    for (int e = tid; e < 4096; e += 256) {
      int c = e >> 6, s = e & 63;
      Kt[s][c] = f2bf(K[(size_t)c * T_LEN + s0 + s]);
      Vt[c][s] = f2bf(V[(size_t)c * T_LEN + s0 + s]);
    }
    __syncthreads();

    // ---- S = Q^T K  (per wave: 16 t-rows x 64 s-cols) ----
    f32x4 s_acc[4];
#pragma unroll
    for (int n = 0; n < 4; ++n) {
      const bf16x8 bk0 = *(const bf16x8*)&Kt[16 * n + l15][l4 * 8];
      const bf16x8 bk1 = *(const bf16x8*)&Kt[16 * n + l15][32 + l4 * 8];
      f32x4 z = (f32x4){0.f, 0.f, 0.f, 0.f};
      z = __builtin_amdgcn_mfma_f32_16x16x32_bf16(aq[0], bk0, z, 0, 0, 0);
      z = __builtin_amdgcn_mfma_f32_16x16x32_bf16(aq[1], bk1, z, 0, 0, 0);
      s_acc[n] = z;
    }

    // ---- online softmax (rows spread over 16 lanes sharing l4) ----
#pragma unroll
    for (int r = 0; r < 4; ++r) {
      float mx = fmaxf(fmaxf(s_acc[0][r], s_acc[1][r]),
                       fmaxf(s_acc[2][r], s_acc[3][r])) * inv64;
#pragma unroll
      for (int off = 8; off >= 1; off >>= 1)
        mx = fmaxf(mx, __shfl_xor(mx, off, 64));
      const float m_new = fmaxf(m_run[r], mx);
      const float alpha = __expf(m_run[r] - m_new);
      float psum = 0.f;
#pragma unroll
      for (int n = 0; n < 4; ++n) {
        float p = __expf(s_acc[n][r] * inv64 - m_new);
        psum += p;
        Pb[wave][l4 * 4 + r][16 * n + l15] = f2bf(p);
      }
#pragma unroll
      for (int off = 8; off >= 1; off >>= 1)
        psum += __shfl_xor(psum, off, 64);
      l_run[r] = l_run[r] * alpha + psum;
      m_run[r] = m_new;
#pragma unroll
      for (int n = 0; n < 4; ++n) o_acc[n][r] *= alpha;
    }

    // ---- O += P V^T  (A = P from LDS in A-layout, B = V) ----
    const bf16x8 ap0 = *(const bf16x8*)&Pb[wave][l15][l4 * 8];
    const bf16x8 ap1 = *(const bf16x8*)&Pb[wave][l15][32 + l4 * 8];
#pragma unroll
    for (int n = 0; n < 4; ++n) {
      const bf16x8 bv0 = *(const bf16x8*)&Vt[16 * n + l15][l4 * 8];
      const bf16x8 bv1 = *(const bf16x8*)&Vt[16 * n + l15][32 + l4 * 8];
      o_acc[n] = __builtin_amdgcn_mfma_f32_16x16x32_bf16(ap0, bv0, o_acc[n], 0, 0, 0);
      o_acc[n] = __builtin_amdgcn_mfma_f32_16x16x32_bf16(ap1, bv1, o_acc[n], 0, 0, 0);
    }
  }

  // ---- epilogue: O[c][t] = o_acc / l ----
#pragma unroll
  for (int n = 0; n < 4; ++n)
#pragma unroll
    for (int r = 0; r < 4; ++r) {
      const int c = 16 * n + l15;
      const int t = t0 + l4 * 4 + r;
      O[(size_t)c * T_LEN + t] = o_acc[n][r] / l_run[r];
    }
}

extern "C" void kernel_launch(void* const* d_in, const int* in_sizes, int n_in,
                              void* d_out, int out_size, void* d_ws, size_t ws_size,
                              hipStream_t stream) {
  const float* qkv = (const float*)d_in[0];
  float* out = (float*)d_out;
  dim3 grid(1024);
  dim3 block(256);
  hipLaunchKernelGGL(attn_fwd, grid, block, 0, stream, qkv, out);
}

// Round 2
// 141.091 us; speedup vs baseline: 1.2458x; 1.2458x over previous
//
#include <hip/hip_runtime.h>
#include <hip/hip_bf16.h>

typedef __attribute__((ext_vector_type(4))) float f32x4;
typedef __attribute__((ext_vector_type(8))) short bf16x8;
typedef __attribute__((ext_vector_type(4))) short s16x4;

#define T_LEN 2048
#define SPAD 72  // 64 + 8 pad (shorts): row stride 144B, 16B-aligned for ds_read_b128

__device__ inline short f2bf(float f) {
  // round-to-nearest-even f32 -> bf16 (inputs finite)
  unsigned u = __builtin_bit_cast(unsigned, f);
  return (short)((u + 0x7fffu + ((u >> 16) & 1u)) >> 16);
}

// ---------------------------------------------------------------------------
// prep_t: fp32 -> bf16 with per-head transpose. sel=0: Q, sel=1: K.
// Output layout: [head][t][c] (c contiguous, 64 bf16 = 128B rows).
// grid = 2048 = sel(2) x head(32) x tchunk(32), block = 256
// ---------------------------------------------------------------------------
__global__ __launch_bounds__(256) void prep_t(const float* __restrict__ qkv,
                                              short* __restrict__ qt,
                                              short* __restrict__ kt) {
  __shared__ float tile[64][65];
  const int bid = blockIdx.x;
  const int tch = bid & 31;
  const int head = (bid >> 5) & 31;
  const int sel = bid >> 10;
  const int b = head >> 3, h = head & 7;
  const float* src = qkv + ((size_t)b * 1536 + sel * 512 + h * 64) * T_LEN + tch * 64;
  short* dst = (sel ? kt : qt) + (size_t)head * T_LEN * 64 + (size_t)tch * 64 * 64;
  const int tid = threadIdx.x;

  for (int e = tid; e < 4096; e += 256) {  // load coalesced along t
    int c = e >> 6, t = e & 63;
    tile[c][t] = src[(size_t)c * T_LEN + t];
  }
  __syncthreads();
  for (int e = tid; e < 2048; e += 256) {  // write coalesced along c (packed 2x bf16)
    int t = e >> 5, c2 = (e & 31) * 2;
    unsigned lo = (unsigned short)f2bf(tile[c2][t]);
    unsigned hi = (unsigned short)f2bf(tile[c2 + 1][t]);
    *(unsigned*)&dst[t * 64 + c2] = lo | (hi << 16);
  }
}

// ---------------------------------------------------------------------------
// prep_v: fp32 -> bf16 straight copy of V (natural [head][c][t] layout).
// grid = 4096, block = 256; each thread converts 4 elements.
// ---------------------------------------------------------------------------
__global__ __launch_bounds__(256) void prep_v(const float* __restrict__ qkv,
                                              short* __restrict__ v_out) {
  typedef __attribute__((ext_vector_type(4))) float f4;
  size_t i = ((size_t)blockIdx.x * 256 + threadIdx.x) * 4;  // total 4*512*2048 exact
  int b = (int)(i / ((size_t)512 * T_LEN));
  size_t r = i % ((size_t)512 * T_LEN);
  f4 s = *(const f4*)&qkv[((size_t)b * 1536 + 1024) * T_LEN + r];
  s16x4 o;
#pragma unroll
  for (int j = 0; j < 4; ++j) o[j] = f2bf(s[j]);
  *(s16x4*)&v_out[i] = o;
}

// ---------------------------------------------------------------------------
// attn2: flash attention, no K/V LDS staging. All MFMA operands loaded as
// 16B global loads from the bf16 prep buffers (L2-resident per head).
// grid = 512 = head(32) x qblk(16); block = 256 (4 waves x 32 q-rows).
// ---------------------------------------------------------------------------
__global__ __launch_bounds__(256) void attn2(const short* __restrict__ Qt,
                                             const short* __restrict__ Kt,
                                             const short* __restrict__ Vb,
                                             float* __restrict__ out) {
  __shared__ short Pb[4][2][16][SPAD];  // [wave][mtile][t_local][s_local]

  const int bid = blockIdx.x;
  const int qblk = bid & 15;
  const int head = bid >> 4;

  const int tid = threadIdx.x;
  const int wave = tid >> 6;
  const int lane = tid & 63;
  const int l15 = lane & 15;
  const int l4 = lane >> 4;

  const int t0 = qblk * 128 + wave * 32;  // this wave's 32 query rows

  const short* Qh = Qt + (size_t)head * T_LEN * 64;
  const short* Kh = Kt + (size_t)head * T_LEN * 64;
  const short* Vh = Vb + (size_t)head * 64 * T_LEN;
  float* O = out + (size_t)head * 64 * T_LEN;

  // Q fragments (A operand): lane holds A[row=t=l15][k=c=l4*8+j]
  bf16x8 aq[2][2];
#pragma unroll
  for (int m = 0; m < 2; ++m)
#pragma unroll
    for (int kk = 0; kk < 2; ++kk)
      aq[m][kk] = *(const bf16x8*)&Qh[(size_t)(t0 + m * 16 + l15) * 64 + kk * 32 + l4 * 8];

  float m_run[2][4], l_run[2][4];
  f32x4 o_acc[2][4];
#pragma unroll
  for (int m = 0; m < 2; ++m)
#pragma unroll
    for (int r = 0; r < 4; ++r) { m_run[m][r] = -1e30f; l_run[m][r] = 0.f; }
#pragma unroll
  for (int m = 0; m < 2; ++m)
#pragma unroll
    for (int n = 0; n < 4; ++n) o_acc[m][n] = (f32x4){0.f, 0.f, 0.f, 0.f};

  const float inv64 = 0.015625f;  // (1/8)^2 folded into scores

  for (int s0 = 0; s0 < T_LEN; s0 += 64) {
    // K fragments (B operand): lane holds B[k=c=l4*8+j][col=s=16n+l15]
    bf16x8 bk[4][2];
#pragma unroll
    for (int n = 0; n < 4; ++n)
#pragma unroll
      for (int kk = 0; kk < 2; ++kk)
        bk[n][kk] = *(const bf16x8*)&Kh[(size_t)(s0 + 16 * n + l15) * 64 + kk * 32 + l4 * 8];

    // S = Q K^T for both M-tiles
    f32x4 sacc[2][4];
#pragma unroll
    for (int m = 0; m < 2; ++m)
#pragma unroll
      for (int n = 0; n < 4; ++n) {
        f32x4 z = (f32x4){0.f, 0.f, 0.f, 0.f};
        z = __builtin_amdgcn_mfma_f32_16x16x32_bf16(aq[m][0], bk[n][0], z, 0, 0, 0);
        z = __builtin_amdgcn_mfma_f32_16x16x32_bf16(aq[m][1], bk[n][1], z, 0, 0, 0);
        sacc[m][n] = z;
      }

    // V fragments issued early so latency hides under softmax:
    // lane holds B[k=s=l4*8+j][col=c=16n+l15]
    bf16x8 bv[4][2];
#pragma unroll
    for (int n = 0; n < 4; ++n)
#pragma unroll
      for (int kk = 0; kk < 2; ++kk)
        bv[n][kk] = *(const bf16x8*)&Vh[(size_t)(16 * n + l15) * T_LEN + s0 + kk * 32 + l4 * 8];

    // online softmax (rows t = t0 + m*16 + l4*4 + r; 16 lanes sharing l4 hold the s-cols)
#pragma unroll
    for (int m = 0; m < 2; ++m)
#pragma unroll
      for (int r = 0; r < 4; ++r) {
        float mx = fmaxf(fmaxf(sacc[m][0][r], sacc[m][1][r]),
                         fmaxf(sacc[m][2][r], sacc[m][3][r])) * inv64;
#pragma unroll
        for (int off = 8; off >= 1; off >>= 1)
          mx = fmaxf(mx, __shfl_xor(mx, off, 64));
        const float m_new = fmaxf(m_run[m][r], mx);
        const float alpha = __expf(m_run[m][r] - m_new);
        float psum = 0.f;
#pragma unroll
        for (int n = 0; n < 4; ++n) {
          float p = __expf(sacc[m][n][r] * inv64 - m_new);
          psum += p;
          Pb[wave][m][l4 * 4 + r][16 * n + l15] = f2bf(p);
        }
#pragma unroll
        for (int off = 8; off >= 1; off >>= 1)
          psum += __shfl_xor(psum, off, 64);
        l_run[m][r] = l_run[m][r] * alpha + psum;
        m_run[m][r] = m_new;
#pragma unroll
        for (int n = 0; n < 4; ++n) o_acc[m][n][r] *= alpha;
      }

    // O += P V^T
#pragma unroll
    for (int m = 0; m < 2; ++m) {
      const bf16x8 ap0 = *(const bf16x8*)&Pb[wave][m][l15][l4 * 8];
      const bf16x8 ap1 = *(const bf16x8*)&Pb[wave][m][l15][32 + l4 * 8];
#pragma unroll
      for (int n = 0; n < 4; ++n) {
        o_acc[m][n] = __builtin_amdgcn_mfma_f32_16x16x32_bf16(ap0, bv[n][0], o_acc[m][n], 0, 0, 0);
        o_acc[m][n] = __builtin_amdgcn_mfma_f32_16x16x32_bf16(ap1, bv[n][1], o_acc[m][n], 0, 0, 0);
      }
    }
  }

  // epilogue: O[c][t] = o / l
#pragma unroll
  for (int m = 0; m < 2; ++m)
#pragma unroll
    for (int n = 0; n < 4; ++n)
#pragma unroll
      for (int r = 0; r < 4; ++r) {
        const int c = 16 * n + l15;
        const int t = t0 + m * 16 + l4 * 4 + r;
        O[(size_t)c * T_LEN + t] = o_acc[m][n][r] / l_run[m][r];
      }
}

// ---------------------------------------------------------------------------
// Fallback (round-1 kernel) if ws_size is too small for the bf16 prep buffers.
// ---------------------------------------------------------------------------
__global__ __launch_bounds__(256) void attn_fwd(const float* __restrict__ qkv,
                                                float* __restrict__ out) {
  __shared__ short KtS[64][SPAD];
  __shared__ short VtS[64][SPAD];
  __shared__ short PbS[4][16][SPAD];

  const int bid = blockIdx.x;
  const int qt = bid & 31;
  const int head = bid >> 5;
  const int b = head >> 3, h = head & 7;

  const size_t base = ((size_t)b * 1536 + h * 64) * T_LEN;
  const float* Q = qkv + base;
  const float* K = qkv + base + (size_t)512 * T_LEN;
  const float* V = qkv + base + (size_t)1024 * T_LEN;
  float* O = out + ((size_t)b * 512 + h * 64) * T_LEN;

  const int tid = threadIdx.x;
  const int wave = tid >> 6;
  const int lane = tid & 63;
  const int l15 = lane & 15;
  const int l4 = lane >> 4;
  const int t0 = qt * 64 + wave * 16;

  bf16x8 aq[2];
#pragma unroll
  for (int kk = 0; kk < 2; ++kk)
#pragma unroll
    for (int j = 0; j < 8; ++j) {
      int c = kk * 32 + l4 * 8 + j;
      aq[kk][j] = f2bf(Q[(size_t)c * T_LEN + t0 + l15]);
    }

  float m_run[4], l_run[4];
  f32x4 o_acc[4];
#pragma unroll
  for (int r = 0; r < 4; ++r) { m_run[r] = -1e30f; l_run[r] = 0.f; }
#pragma unroll
  for (int n = 0; n < 4; ++n) o_acc[n] = (f32x4){0.f, 0.f, 0.f, 0.f};

  const float inv64 = 0.015625f;

  for (int s0 = 0; s0 < T_LEN; s0 += 64) {
    __syncthreads();
    for (int e = tid; e < 4096; e += 256) {
      int c = e >> 6, s = e & 63;
      KtS[s][c] = f2bf(K[(size_t)c * T_LEN + s0 + s]);
      VtS[c][s] = f2bf(V[(size_t)c * T_LEN + s0 + s]);
    }
    __syncthreads();

    f32x4 sacc[4];
#pragma unroll
    for (int n = 0; n < 4; ++n) {
      const bf16x8 bk0 = *(const bf16x8*)&KtS[16 * n + l15][l4 * 8];
      const bf16x8 bk1 = *(const bf16x8*)&KtS[16 * n + l15][32 + l4 * 8];
      f32x4 z = (f32x4){0.f, 0.f, 0.f, 0.f};
      z = __builtin_amdgcn_mfma_f32_16x16x32_bf16(aq[0], bk0, z, 0, 0, 0);
      z = __builtin_amdgcn_mfma_f32_16x16x32_bf16(aq[1], bk1, z, 0, 0, 0);
      sacc[n] = z;
    }

#pragma unroll
    for (int r = 0; r < 4; ++r) {
      float mx = fmaxf(fmaxf(sacc[0][r], sacc[1][r]),
                       fmaxf(sacc[2][r], sacc[3][r])) * inv64;
#pragma unroll
      for (int off = 8; off >= 1; off >>= 1)
        mx = fmaxf(mx, __shfl_xor(mx, off, 64));
      const float m_new = fmaxf(m_run[r], mx);
      const float alpha = __expf(m_run[r] - m_new);
      float psum = 0.f;
#pragma unroll
      for (int n = 0; n < 4; ++n) {
        float p = __expf(sacc[n][r] * inv64 - m_new);
        psum += p;
        PbS[wave][l4 * 4 + r][16 * n + l15] = f2bf(p);
      }
#pragma unroll
      for (int off = 8; off >= 1; off >>= 1)
        psum += __shfl_xor(psum, off, 64);
      l_run[r] = l_run[r] * alpha + psum;
      m_run[r] = m_new;
#pragma unroll
      for (int n = 0; n < 4; ++n) o_acc[n][r] *= alpha;
    }

    const bf16x8 ap0 = *(const bf16x8*)&PbS[wave][l15][l4 * 8];
    const bf16x8 ap1 = *(const bf16x8*)&PbS[wave][l15][32 + l4 * 8];
#pragma unroll
    for (int n = 0; n < 4; ++n) {
      const bf16x8 bv0 = *(const bf16x8*)&VtS[16 * n + l15][l4 * 8];
      const bf16x8 bv1 = *(const bf16x8*)&VtS[16 * n + l15][32 + l4 * 8];
      o_acc[n] = __builtin_amdgcn_mfma_f32_16x16x32_bf16(ap0, bv0, o_acc[n], 0, 0, 0);
      o_acc[n] = __builtin_amdgcn_mfma_f32_16x16x32_bf16(ap1, bv1, o_acc[n], 0, 0, 0);
    }
  }

#pragma unroll
  for (int n = 0; n < 4; ++n)
#pragma unroll
    for (int r = 0; r < 4; ++r) {
      const int c = 16 * n + l15;
      const int t = t0 + l4 * 4 + r;
      O[(size_t)c * T_LEN + t] = o_acc[n][r] / l_run[r];
    }
}

extern "C" void kernel_launch(void* const* d_in, const int* in_sizes, int n_in,
                              void* d_out, int out_size, void* d_ws, size_t ws_size,
                              hipStream_t stream) {
  const float* qkv = (const float*)d_in[0];
  float* out = (float*)d_out;
  const size_t per_buf = (size_t)32 * T_LEN * 64;  // shorts per Q/K/V buffer
  const size_t need = per_buf * 3 * sizeof(short); // 24 MB
  if (ws_size >= need) {
    short* qt = (short*)d_ws;
    short* kt = qt + per_buf;
    short* vb = kt + per_buf;
    hipLaunchKernelGGL(prep_t, dim3(2048), dim3(256), 0, stream, qkv, qt, kt);
    hipLaunchKernelGGL(prep_v, dim3(4096), dim3(256), 0, stream, qkv, vb);
    hipLaunchKernelGGL(attn2, dim3(512), dim3(256), 0, stream, qt, kt, vb, out);
  } else {
    hipLaunchKernelGGL(attn_fwd, dim3(1024), dim3(256), 0, stream, qkv, out);
  }
}

// Round 3
// 140.022 us; speedup vs baseline: 1.2554x; 1.0076x over previous
//
#include <hip/hip_runtime.h>
#include <hip/hip_bf16.h>

typedef __attribute__((ext_vector_type(4))) float f32x4;
typedef __attribute__((ext_vector_type(8))) short bf16x8;
typedef __attribute__((ext_vector_type(4))) short s16x4;

#define T_LEN 2048
#define SPAD 72  // 64 + 8 pad (shorts): row stride 144B, 16B-aligned for ds_read_b128

__device__ inline short f2bf(float f) {
  unsigned u = __builtin_bit_cast(unsigned, f);
  return (short)((u + 0x7fffu + ((u >> 16) & 1u)) >> 16);
}

// ---------------------------------------------------------------------------
// prep_t: fp32 -> bf16 with per-head transpose. sel=0: Q, sel=1: K.
// Output layout: [head][t][c]. grid = 2048, block = 256.
// ---------------------------------------------------------------------------
__global__ __launch_bounds__(256) void prep_t(const float* __restrict__ qkv,
                                              short* __restrict__ qt,
                                              short* __restrict__ kt) {
  __shared__ float tile[64][65];
  const int bid = blockIdx.x;
  const int tch = bid & 31;
  const int head = (bid >> 5) & 31;
  const int sel = bid >> 10;
  const int b = head >> 3, h = head & 7;
  const float* src = qkv + ((size_t)b * 1536 + sel * 512 + h * 64) * T_LEN + tch * 64;
  short* dst = (sel ? kt : qt) + (size_t)head * T_LEN * 64 + (size_t)tch * 64 * 64;
  const int tid = threadIdx.x;

  for (int e = tid; e < 4096; e += 256) {
    int c = e >> 6, t = e & 63;
    tile[c][t] = src[(size_t)c * T_LEN + t];
  }
  __syncthreads();
  for (int e = tid; e < 2048; e += 256) {
    int t = e >> 5, c2 = (e & 31) * 2;
    unsigned lo = (unsigned short)f2bf(tile[c2][t]);
    unsigned hi = (unsigned short)f2bf(tile[c2 + 1][t]);
    *(unsigned*)&dst[t * 64 + c2] = lo | (hi << 16);
  }
}

// ---------------------------------------------------------------------------
// prep_v: fp32 -> bf16 straight copy of V ([head][c][t]). grid = 4096.
// ---------------------------------------------------------------------------
__global__ __launch_bounds__(256) void prep_v(const float* __restrict__ qkv,
                                              short* __restrict__ v_out) {
  typedef __attribute__((ext_vector_type(4))) float f4;
  size_t i = ((size_t)blockIdx.x * 256 + threadIdx.x) * 4;
  int b = (int)(i / ((size_t)512 * T_LEN));
  size_t r = i % ((size_t)512 * T_LEN);
  f4 s = *(const f4*)&qkv[((size_t)b * 1536 + 1024) * T_LEN + r];
  s16x4 o;
#pragma unroll
  for (int j = 0; j < 4; ++j) o[j] = f2bf(s[j]);
  *(s16x4*)&v_out[i] = o;
}

// ---------------------------------------------------------------------------
// attn3: flash attention. Direct global bf16 MFMA fragment loads (L2-hot),
// K-fragment register double-buffering, defer-max softmax (exp2 domain),
// per-lane partial row-sums (epilogue reduce). grid = 512, block = 256.
// ---------------------------------------------------------------------------
__global__ __launch_bounds__(256, 2) void attn3(const short* __restrict__ Qt,
                                                const short* __restrict__ Kt,
                                                const short* __restrict__ Vb,
                                                float* __restrict__ out) {
  __shared__ short Pb[4][2][16][SPAD];  // [wave][mtile][t_local][s_local]

  const int bid = blockIdx.x;
  const int qblk = bid & 15;
  const int head = bid >> 4;

  const int tid = threadIdx.x;
  const int wave = tid >> 6;
  const int lane = tid & 63;
  const int l15 = lane & 15;
  const int l4 = lane >> 4;

  const int t0 = qblk * 128 + wave * 32;

  const short* Qh = Qt + (size_t)head * T_LEN * 64;
  const short* Kh = Kt + (size_t)head * T_LEN * 64;
  const short* Vh = Vb + (size_t)head * 64 * T_LEN;
  float* O = out + (size_t)head * 64 * T_LEN;

  // Q fragments (A): lane holds A[row=t=l15][k=c=l4*8+j]
  bf16x8 aq[2][2];
#pragma unroll
  for (int m = 0; m < 2; ++m)
#pragma unroll
    for (int kk = 0; kk < 2; ++kk)
      aq[m][kk] = *(const bf16x8*)&Qh[(size_t)(t0 + m * 16 + l15) * 64 + kk * 32 + l4 * 8];

  const float K2 = 0.0225421101f;  // log2(e) / 64  (both scale factors folded)
  const float THR = 8.0f;          // defer-max threshold, exp2 domain

  float m2[2][4], l_lane[2][4];
  f32x4 o_acc[2][4];
#pragma unroll
  for (int m = 0; m < 2; ++m)
#pragma unroll
    for (int r = 0; r < 4; ++r) { m2[m][r] = -1e30f; l_lane[m][r] = 0.f; }
#pragma unroll
  for (int m = 0; m < 2; ++m)
#pragma unroll
    for (int n = 0; n < 4; ++n) o_acc[m][n] = (f32x4){0.f, 0.f, 0.f, 0.f};

  // B-layout loads: lane holds B[k=l4*8+j][col=16n+l15]
  auto load_k = [&](bf16x8(&bk)[4][2], int s0) {
#pragma unroll
    for (int n = 0; n < 4; ++n)
#pragma unroll
      for (int kk = 0; kk < 2; ++kk)
        bk[n][kk] = *(const bf16x8*)&Kh[(size_t)(s0 + 16 * n + l15) * 64 + kk * 32 + l4 * 8];
  };
  auto load_v = [&](bf16x8(&bv)[4][2], int s0) {
#pragma unroll
    for (int n = 0; n < 4; ++n)
#pragma unroll
      for (int kk = 0; kk < 2; ++kk)
        bv[n][kk] = *(const bf16x8*)&Vh[(size_t)(16 * n + l15) * T_LEN + s0 + kk * 32 + l4 * 8];
  };
  auto qk_phase = [&](const bf16x8(&bk)[4][2], f32x4(&sacc)[2][4]) {
#pragma unroll
    for (int m = 0; m < 2; ++m)
#pragma unroll
      for (int n = 0; n < 4; ++n) {
        f32x4 z = (f32x4){0.f, 0.f, 0.f, 0.f};
        z = __builtin_amdgcn_mfma_f32_16x16x32_bf16(aq[m][0], bk[n][0], z, 0, 0, 0);
        z = __builtin_amdgcn_mfma_f32_16x16x32_bf16(aq[m][1], bk[n][1], z, 0, 0, 0);
        sacc[m][n] = z;
      }
  };
  auto soft_pv = [&](f32x4(&sacc)[2][4], const bf16x8(&bv)[4][2]) {
#pragma unroll
    for (int m = 0; m < 2; ++m) {
      float rmax[4];
#pragma unroll
      for (int r = 0; r < 4; ++r)
        rmax[r] = fmaxf(fmaxf(sacc[m][0][r], sacc[m][1][r]),
                        fmaxf(sacc[m][2][r], sacc[m][3][r])) * K2;
      int ok = 1;
#pragma unroll
      for (int r = 0; r < 4; ++r) ok &= (rmax[r] <= m2[m][r] + THR) ? 1 : 0;
      if (!__all(ok)) {  // rare: tile 0 (and pathological max growth) only
#pragma unroll
        for (int r = 0; r < 4; ++r) {
          float mx = rmax[r];
#pragma unroll
          for (int off = 8; off >= 1; off >>= 1)
            mx = fmaxf(mx, __shfl_xor(mx, off, 64));
          const float mnew = fmaxf(m2[m][r], mx);
          const float alpha = exp2f(m2[m][r] - mnew);
          m2[m][r] = mnew;
          l_lane[m][r] *= alpha;
#pragma unroll
          for (int n = 0; n < 4; ++n) o_acc[m][n][r] *= alpha;
        }
      }
#pragma unroll
      for (int r = 0; r < 4; ++r) {
        float ps = 0.f;
#pragma unroll
        for (int n = 0; n < 4; ++n) {
          float p = exp2f(__builtin_fmaf(sacc[m][n][r], K2, -m2[m][r]));
          ps += p;
          __hip_bfloat16 hb = __float2bfloat16(p);
          Pb[wave][m][l4 * 4 + r][16 * n + l15] = *(short*)&hb;
        }
        l_lane[m][r] += ps;  // per-lane partial; reduced once in epilogue
      }
    }
#pragma unroll
    for (int m = 0; m < 2; ++m) {
      const bf16x8 ap0 = *(const bf16x8*)&Pb[wave][m][l15][l4 * 8];
      const bf16x8 ap1 = *(const bf16x8*)&Pb[wave][m][l15][32 + l4 * 8];
#pragma unroll
      for (int n = 0; n < 4; ++n) {
        o_acc[m][n] = __builtin_amdgcn_mfma_f32_16x16x32_bf16(ap0, bv[n][0], o_acc[m][n], 0, 0, 0);
        o_acc[m][n] = __builtin_amdgcn_mfma_f32_16x16x32_bf16(ap1, bv[n][1], o_acc[m][n], 0, 0, 0);
      }
    }
  };

  bf16x8 bkA[4][2], bkB[4][2], bv[4][2];
  f32x4 sacc[2][4];

  load_k(bkA, 0);
  for (int s0 = 0; s0 < T_LEN; s0 += 128) {
    // phase A: keys [s0, s0+64)
    qk_phase(bkA, sacc);
    load_k(bkB, s0 + 64);          // prefetch next K under softmax
    load_v(bv, s0);                // V latency hidden under softmax
    soft_pv(sacc, bv);
    // phase B: keys [s0+64, s0+128)
    qk_phase(bkB, sacc);
    if (s0 + 128 < T_LEN) load_k(bkA, s0 + 128);
    load_v(bv, s0 + 64);
    soft_pv(sacc, bv);
  }

  // epilogue: reduce per-lane partial l across the 16 lanes sharing each row
#pragma unroll
  for (int m = 0; m < 2; ++m)
#pragma unroll
    for (int r = 0; r < 4; ++r) {
      float l = l_lane[m][r];
#pragma unroll
      for (int off = 8; off >= 1; off >>= 1) l += __shfl_xor(l, off, 64);
      const float rl = 1.0f / l;
      const int t = t0 + m * 16 + l4 * 4 + r;
#pragma unroll
      for (int n = 0; n < 4; ++n)
        O[(size_t)(16 * n + l15) * T_LEN + t] = o_acc[m][n][r] * rl;
    }
}

// ---------------------------------------------------------------------------
// Fallback (round-1 kernel) if ws_size is too small for the bf16 prep buffers.
// ---------------------------------------------------------------------------
__global__ __launch_bounds__(256) void attn_fwd(const float* __restrict__ qkv,
                                                float* __restrict__ out) {
  __shared__ short KtS[64][SPAD];
  __shared__ short VtS[64][SPAD];
  __shared__ short PbS[4][16][SPAD];

  const int bid = blockIdx.x;
  const int qt = bid & 31;
  const int head = bid >> 5;
  const int b = head >> 3, h = head & 7;

  const size_t base = ((size_t)b * 1536 + h * 64) * T_LEN;
  const float* Q = qkv + base;
  const float* K = qkv + base + (size_t)512 * T_LEN;
  const float* V = qkv + base + (size_t)1024 * T_LEN;
  float* O = out + ((size_t)b * 512 + h * 64) * T_LEN;

  const int tid = threadIdx.x;
  const int wave = tid >> 6;
  const int lane = tid & 63;
  const int l15 = lane & 15;
  const int l4 = lane >> 4;
  const int t0 = qt * 64 + wave * 16;

  bf16x8 aq[2];
#pragma unroll
  for (int kk = 0; kk < 2; ++kk)
#pragma unroll
    for (int j = 0; j < 8; ++j) {
      int c = kk * 32 + l4 * 8 + j;
      aq[kk][j] = f2bf(Q[(size_t)c * T_LEN + t0 + l15]);
    }

  float m_run[4], l_run[4];
  f32x4 o_acc[4];
#pragma unroll
  for (int r = 0; r < 4; ++r) { m_run[r] = -1e30f; l_run[r] = 0.f; }
#pragma unroll
  for (int n = 0; n < 4; ++n) o_acc[n] = (f32x4){0.f, 0.f, 0.f, 0.f};

  const float inv64 = 0.015625f;

  for (int s0 = 0; s0 < T_LEN; s0 += 64) {
    __syncthreads();
    for (int e = tid; e < 4096; e += 256) {
      int c = e >> 6, s = e & 63;
      KtS[s][c] = f2bf(K[(size_t)c * T_LEN + s0 + s]);
      VtS[c][s] = f2bf(V[(size_t)c * T_LEN + s0 + s]);
    }
    __syncthreads();

    f32x4 sacc[4];
#pragma unroll
    for (int n = 0; n < 4; ++n) {
      const bf16x8 bk0 = *(const bf16x8*)&KtS[16 * n + l15][l4 * 8];
      const bf16x8 bk1 = *(const bf16x8*)&KtS[16 * n + l15][32 + l4 * 8];
      f32x4 z = (f32x4){0.f, 0.f, 0.f, 0.f};
      z = __builtin_amdgcn_mfma_f32_16x16x32_bf16(aq[0], bk0, z, 0, 0, 0);
      z = __builtin_amdgcn_mfma_f32_16x16x32_bf16(aq[1], bk1, z, 0, 0, 0);
      sacc[n] = z;
    }

#pragma unroll
    for (int r = 0; r < 4; ++r) {
      float mx = fmaxf(fmaxf(sacc[0][r], sacc[1][r]),
                       fmaxf(sacc[2][r], sacc[3][r])) * inv64;
#pragma unroll
      for (int off = 8; off >= 1; off >>= 1)
        mx = fmaxf(mx, __shfl_xor(mx, off, 64));
      const float m_new = fmaxf(m_run[r], mx);
      const float alpha = __expf(m_run[r] - m_new);
      float psum = 0.f;
#pragma unroll
      for (int n = 0; n < 4; ++n) {
        float p = __expf(sacc[n][r] * inv64 - m_new);
        psum += p;
        PbS[wave][l4 * 4 + r][16 * n + l15] = f2bf(p);
      }
#pragma unroll
      for (int off = 8; off >= 1; off >>= 1)
        psum += __shfl_xor(psum, off, 64);
      l_run[r] = l_run[r] * alpha + psum;
      m_run[r] = m_new;
#pragma unroll
      for (int n = 0; n < 4; ++n) o_acc[n][r] *= alpha;
    }

    const bf16x8 ap0 = *(const bf16x8*)&PbS[wave][l15][l4 * 8];
    const bf16x8 ap1 = *(const bf16x8*)&PbS[wave][l15][32 + l4 * 8];
#pragma unroll
    for (int n = 0; n < 4; ++n) {
      const bf16x8 bv0 = *(const bf16x8*)&VtS[16 * n + l15][l4 * 8];
      const bf16x8 bv1 = *(const bf16x8*)&VtS[16 * n + l15][32 + l4 * 8];
      o_acc[n] = __builtin_amdgcn_mfma_f32_16x16x32_bf16(ap0, bv0, o_acc[n], 0, 0, 0);
      o_acc[n] = __builtin_amdgcn_mfma_f32_16x16x32_bf16(ap1, bv1, o_acc[n], 0, 0, 0);
    }
  }

#pragma unroll
  for (int n = 0; n < 4; ++n)
#pragma unroll
    for (int r = 0; r < 4; ++r) {
      const int c = 16 * n + l15;
      const int t = t0 + l4 * 4 + r;
      O[(size_t)c * T_LEN + t] = o_acc[n][r] / l_run[r];
    }
}

extern "C" void kernel_launch(void* const* d_in, const int* in_sizes, int n_in,
                              void* d_out, int out_size, void* d_ws, size_t ws_size,
                              hipStream_t stream) {
  const float* qkv = (const float*)d_in[0];
  float* out = (float*)d_out;
  const size_t per_buf = (size_t)32 * T_LEN * 64;  // shorts per Q/K/V buffer
  const size_t need = per_buf * 3 * sizeof(short); // 24 MB
  if (ws_size >= need) {
    short* qt = (short*)d_ws;
    short* kt = qt + per_buf;
    short* vb = kt + per_buf;
    hipLaunchKernelGGL(prep_t, dim3(2048), dim3(256), 0, stream, qkv, qt, kt);
    hipLaunchKernelGGL(prep_v, dim3(4096), dim3(256), 0, stream, qkv, vb);
    hipLaunchKernelGGL(attn3, dim3(512), dim3(256), 0, stream, qt, kt, vb, out);
  } else {
    hipLaunchKernelGGL(attn_fwd, dim3(1024), dim3(256), 0, stream, qkv, out);
  }
}